// Round 3
// baseline (808.498 us; speedup 1.0000x reference)
//
#include <hip/hip_runtime.h>
#include <math.h>

#define T 8
#define NI 20000
#define NK 50000
#define F 128
#define H 256
#define O 128
#define E 500000
#define G3 (3*H)          // 768
#define MAXS 256          // slot cap per timestep (E[slots]=25)
#define CAP1 256          // per-slot e1 edge cap (E[edges/slot]=10)
#define BMW 1568          // ceil(NK/32)
#define NB 8              // persistent GRU blocks
#define RPB 32            // h-indices per GRU block (H/NB)
#define EQ (E/4)          // int4 quads per timestep
#define SENT 0xFFFFFFFFu  // rnn sentinel (NaN bit pattern, unreachable)

// ---------------- workspace layout (bytes) ----------------
// zeroed prefix:
#define OFF_CNT2   0                        // T ints
#define OFF_ITEMS  32                       // T*MAXS ints
#define OFF_CNT1   (32 + T*MAXS*4)          // T*MAXS ints
#define OFF_HSUM   (OFF_CNT1 + T*MAXS*4)    // T*H floats
#define WS_ZERO    (OFF_HSUM + T*H*4)
// bitmap (zeroed separately—kept in zero prefix):
#define OFF_GBM    WS_ZERO                  // T*BMW uints
#define WS_ZERO2   (OFF_GBM + T*BMW*4)      // ~73 KB memset total
// not zeroed (fully written before read):
#define OFF_LIST1  WS_ZERO2                 // T*MAXS*CAP1 ints (2 MB)
// sentinel-filled (0xFF memset):
#define OFF_RNN    (OFF_LIST1 + (size_t)T*MAXS*CAP1*4)  // T*H floats
#define WS_USED    (OFF_RNN + T*H*4)

// K1: scan e2_dst (int4) for edges into target; record src items (slots),
// set global item bitmap.
__global__ void k_find_e2(const int* __restrict__ e2_src, const int* __restrict__ e2_dst,
                          const int* __restrict__ target_p,
                          int* __restrict__ cnt2, int* __restrict__ items,
                          unsigned* __restrict__ gbm) {
    int t = blockIdx.y;
    long q = (long)blockIdx.x * 256 + threadIdx.x;
    if (q >= EQ) return;
    int target = *target_p;
    const int4 d4 = ((const int4*)(e2_dst + (long)t * E))[q];
    int dd[4] = {d4.x, d4.y, d4.z, d4.w};
#pragma unroll
    for (int c = 0; c < 4; ++c) {
        if (dd[c] == target) {
            long j = q * 4 + c;
            int src = e2_src[(long)t * E + j];
            int pos = atomicAdd(&cnt2[t], 1);
            if (pos < MAXS) {
                items[t * MAXS + pos] = src;
                atomicOr(&gbm[t * BMW + (src >> 5)], 1u << (src & 31));
            }
        }
    }
}

// K2: scan e1_dst (int4) against global bitmap; matching edges append their
// src index into the slot's list.
__global__ void k_scan_e1(const int* __restrict__ e1_src, const int* __restrict__ e1_dst,
                          const int* __restrict__ cnt2, const int* __restrict__ items,
                          const unsigned* __restrict__ gbm,
                          int* __restrict__ cnt1, int* __restrict__ list1) {
    int t = blockIdx.y;
    long q = (long)blockIdx.x * 256 + threadIdx.x;
    if (q >= EQ) return;
    const unsigned* bm = gbm + t * BMW;
    const int4 d4 = ((const int4*)(e1_dst + (long)t * E))[q];
    int dd[4] = {d4.x, d4.y, d4.z, d4.w};
#pragma unroll
    for (int c = 0; c < 4; ++c) {
        int d = dd[c];
        if (!((bm[d >> 5] >> (d & 31)) & 1u)) continue;
        long j = q * 4 + c;
        int src = e1_src[(long)t * E + j];
        int ns = min(cnt2[t], MAXS);
        for (int i = 0; i < ns; ++i) {
            if (items[t * MAXS + i] == d) {
                int pos = atomicAdd(&cnt1[t * MAXS + i], 1);
                if (pos < CAP1) list1[((long)t * MAXS + i) * CAP1 + pos] = src;
            }
        }
    }
}

// K3: per slot, gather its e1 srcs, mean, then
// h_item = relu(mean @ W1a_l.T + b1a_l + x_item @ W1a_r.T); sum into hsum.
__global__ void k_hitem(const float* __restrict__ x_item, const float* __restrict__ x_inf,
                        const float* __restrict__ W1a_l, const float* __restrict__ b1a_l,
                        const float* __restrict__ W1a_r,
                        const int* __restrict__ cnt2, const int* __restrict__ items,
                        const int* __restrict__ cnt1, const int* __restrict__ list1,
                        float* __restrict__ hsum) {
    int t = blockIdx.y, slot = blockIdx.x;
    int ns = min(cnt2[t], MAXS);
    if (slot >= ns) return;
    __shared__ float z1[F], xk[F];
    int item = items[t * MAXS + slot];
    int ne = cnt1[t * MAXS + slot];
    float inv = 1.0f / fmaxf((float)ne, 1.0f);
    int nr = min(ne, CAP1);
    if (threadIdx.x < F) {
        int f = threadIdx.x;
        const int* lst = list1 + ((long)t * MAXS + slot) * CAP1;
        float s = 0.0f;
        for (int e = 0; e < nr; ++e)
            s += x_inf[((long)t * NI + lst[e]) * F + f];
        z1[f] = s * inv;
        xk[f] = x_item[((long)t * NK + item) * F + f];
    }
    __syncthreads();
    int h = threadIdx.x;  // 256 == H
    float acc = b1a_l[h];
    const float* wl = W1a_l + h * F;
    const float* wr = W1a_r + h * F;
    for (int f = 0; f < F; ++f) acc += z1[f] * wl[f] + xk[f] * wr[f];
    acc = fmaxf(acc, 0.0f);
    atomicAdd(&hsum[t * H + h], acc);
}

// K4 v3: fused tail with NO inter-block barriers or fences.
// Each block redundantly computes o[t] for all t (weights L2/IC-shared),
// then its own 96 gi rows locally into LDS. The recurrence exchanges h via
// sentinel-stamped relaxed agent-scope atomics on rnn (data-as-flag).
// Block 0 runs attention + head at the end (from its srnn copy).
__global__ void __launch_bounds__(256, 1)
k_gru(const float* __restrict__ x_inf, const float* __restrict__ x_item,
      const int* __restrict__ target_p,
      const float* __restrict__ W1b_l, const float* __restrict__ b1b_l,
      const float* __restrict__ W1b_r,
      const float* __restrict__ W2b_l, const float* __restrict__ b2b_l,
      const float* __restrict__ W2b_r,
      const int* __restrict__ cnt2, const int* __restrict__ items,
      const float* __restrict__ hsum,
      const float* __restrict__ W_ih, const float* __restrict__ b_ih,
      const float* __restrict__ W_hh, const float* __restrict__ b_hh,
      const float* __restrict__ W_att, const float* __restrict__ b_att,
      const float* __restrict__ W_p1, const float* __restrict__ b_p1,
      const float* __restrict__ W_p2, const float* __restrict__ b_p2,
      float* __restrict__ rnn, float* __restrict__ out) {
    __shared__ float w[3 * RPB][H];   // 96 KiB
    __shared__ float h[H];
    __shared__ float srnn[T][H];      // 8 KiB
    __shared__ float satt[T], tmp[H], hid[128];
    __shared__ float z2a[T][F], xta[T][F];    // 8 KiB
    __shared__ float mha[T][H], hinfa[T][H];  // 16 KiB
    __shared__ float so_all[T][O];    // 4 KiB
    __shared__ float sgi[T][3][RPB];  // 3 KiB
    int b = blockIdx.x, tid = threadIdx.x;
    int wv = tid >> 6, lane = tid & 63;
    unsigned* rnn_u = (unsigned*)rnn;

    // W_hh slice -> LDS (issued first; overlaps with the gathers below)
    for (int idx = tid; idx < 3 * RPB * H; idx += 256) {
        int r = idx >> 8, k = idx & 255;
        int g = r / RPB, j = r - g * RPB;
        w[r][k] = W_hh[((long)(g * H + b * RPB + j)) * H + k];
    }

    // ---- phase 1 (all t, redundant per block): gathers ----
    int target = *target_p;
    for (int p = tid; p < T * F; p += 256) {
        int t = p >> 7, f = p & 127;
        int ns = min(cnt2[t], MAXS);
        float c2 = fmaxf((float)cnt2[t], 1.0f);
        float s = 0.0f;
        for (int i = 0; i < ns; ++i)
            s += x_item[((long)t * NK + items[t * MAXS + i]) * F + f];
        z2a[t][f] = s / c2;
        xta[t][f] = x_inf[((long)t * NI + target) * F + f];
    }
    for (int p = tid; p < T * H; p += 256) {
        int t = p >> 8, k = p & 255;
        float c2 = fmaxf((float)cnt2[t], 1.0f);
        mha[t][k] = hsum[t * H + k] / c2;
    }
    __syncthreads();
    // hinf rows: weights cached in regs, reused across t
    for (int r = wv; r < H; r += 4) {
        float wl0 = W1b_l[r * F + lane], wl1 = W1b_l[r * F + 64 + lane];
        float wr0 = W1b_r[r * F + lane], wr1 = W1b_r[r * F + 64 + lane];
        float bb = b1b_l[r];
        for (int t = 0; t < T; ++t) {
            float s = wl0 * z2a[t][lane] + wl1 * z2a[t][lane + 64]
                    + wr0 * xta[t][lane] + wr1 * xta[t][lane + 64];
            for (int off = 32; off; off >>= 1) s += __shfl_down(s, off);
            if (lane == 0) hinfa[t][r] = fmaxf(s + bb, 0.0f);
        }
    }
    __syncthreads();
    // o rows
    for (int r = wv; r < O; r += 4) {
        float a0 = W2b_l[r * H + lane],       a1 = W2b_l[r * H + 64 + lane];
        float a2 = W2b_l[r * H + 128 + lane], a3 = W2b_l[r * H + 192 + lane];
        float c0 = W2b_r[r * H + lane],       c1 = W2b_r[r * H + 64 + lane];
        float c2_ = W2b_r[r * H + 128 + lane], c3 = W2b_r[r * H + 192 + lane];
        float bb = b2b_l[r];
        for (int t = 0; t < T; ++t) {
            float s = a0 * mha[t][lane]       + c0 * hinfa[t][lane]
                    + a1 * mha[t][lane + 64]  + c1 * hinfa[t][lane + 64]
                    + a2 * mha[t][lane + 128] + c2_ * hinfa[t][lane + 128]
                    + a3 * mha[t][lane + 192] + c3 * hinfa[t][lane + 192];
            for (int off = 32; off; off >>= 1) s += __shfl_down(s, off);
            if (lane == 0) so_all[t][r] = s + bb;
        }
    }
    __syncthreads();
    // ---- phase 2: own gi rows only, into LDS ----
    for (int lr = wv; lr < 3 * RPB; lr += 4) {
        int g = lr >> 5, j = lr & 31;
        int r = g * H + b * RPB + j;
        float w0 = W_ih[(long)r * O + lane];
        float w1 = W_ih[(long)r * O + 64 + lane];
        float bi = b_ih[r];
        for (int t = 0; t < T; ++t) {
            float s = w0 * so_all[t][lane] + w1 * so_all[t][lane + 64];
            for (int off = 32; off; off >>= 1) s += __shfl_down(s, off);
            if (lane == 0) sgi[t][g][j] = s + bi;
        }
    }
    h[tid] = 0.0f;
    __syncthreads();

    // ---- GRU recurrence: h exchanged via sentinel data spins ----
    for (int t = 0; t < T; ++t) {
        for (int j = wv; j < RPB; j += 4) {
            float sr = 0.f, sz = 0.f, sn = 0.f;
            for (int c = 0; c < 4; ++c) {
                int k = lane + 64 * c;
                float hk = h[k];
                sr += w[j][k] * hk;
                sz += w[RPB + j][k] * hk;
                sn += w[2 * RPB + j][k] * hk;
            }
            for (int off = 32; off; off >>= 1) {
                sr += __shfl_down(sr, off);
                sz += __shfl_down(sz, off);
                sn += __shfl_down(sn, off);
            }
            if (lane == 0) {
                int i = b * RPB + j;
                float r = 1.0f / (1.0f + expf(-(sgi[t][0][j] + sr + b_hh[i])));
                float z = 1.0f / (1.0f + expf(-(sgi[t][1][j] + sz + b_hh[H + i])));
                float n = tanhf(sgi[t][2][j] + r * (sn + b_hh[2 * H + i]));
                float hn = (1.0f - z) * n + z * h[i];
                __hip_atomic_store(&rnn_u[t * H + i], __float_as_uint(hn),
                                   __ATOMIC_RELAXED, __HIP_MEMORY_SCOPE_AGENT);
            }
        }
        __syncthreads();   // all waves done reading old h
        unsigned v;
        do {
            v = __hip_atomic_load(&rnn_u[t * H + tid], __ATOMIC_RELAXED,
                                  __HIP_MEMORY_SCOPE_AGENT);
            if (v != SENT) break;
            __builtin_amdgcn_s_sleep(1);
        } while (true);
        float hv = __uint_as_float(v);
        h[tid] = hv;
        srnn[t][tid] = hv;
        __syncthreads();   // h ready for next step
    }
    if (b != 0) return;
    // ---- attention + head (block 0, from srnn) ----
    {   // att scores: 32 lanes per t
        int tt = tid >> 5, l32 = tid & 31;
        float a = 0.f;
        for (int c = 0; c < 8; ++c) {
            int k = l32 + 32 * c;
            a += W_att[k] * srnn[tt][k];
        }
        for (int off = 16; off; off >>= 1) a += __shfl_down(a, off, 32);
        if (l32 == 0) satt[tt] = a + b_att[0];
    }
    __syncthreads();
    if (tid == 0) {
        float m = satt[0];
        for (int t = 1; t < T; ++t) m = fmaxf(m, satt[t]);
        float s = 0.f;
        for (int t = 0; t < T; ++t) { satt[t] = expf(satt[t] - m); s += satt[t]; }
        for (int t = 0; t < T; ++t) satt[t] /= s;
    }
    __syncthreads();
    {
        float ctx = 0.f;
        for (int t = 0; t < T; ++t) ctx += satt[t] * srnn[t][tid];
        tmp[tid] = ctx;
    }
    __syncthreads();
    if (tid < 128) {
        float a = b_p1[tid];
        const float* wp = W_p1 + (long)tid * H;
        for (int k = 0; k < H; ++k) a += wp[k] * tmp[k];
        hid[tid] = fmaxf(a, 0.0f);
    }
    __syncthreads();
    if (tid == 0) {
        float s = b_p2[0];
        for (int k = 0; k < 128; ++k) s += W_p2[k] * hid[k];
        out[0] = s;
    }
}

extern "C" void kernel_launch(void* const* d_in, const int* in_sizes, int n_in,
                              void* d_out, int out_size, void* d_ws, size_t ws_size,
                              hipStream_t stream) {
    const float* x_inf  = (const float*)d_in[0];
    const float* x_item = (const float*)d_in[1];
    const int* e1_src = (const int*)d_in[2];
    const int* e1_dst = (const int*)d_in[3];
    const int* e2_src = (const int*)d_in[4];
    const int* e2_dst = (const int*)d_in[5];
    const int* target_p = (const int*)d_in[6];
    const float* W1a_l = (const float*)d_in[7];
    const float* b1a_l = (const float*)d_in[8];
    const float* W1a_r = (const float*)d_in[9];
    const float* W1b_l = (const float*)d_in[10];
    const float* b1b_l = (const float*)d_in[11];
    const float* W1b_r = (const float*)d_in[12];
    const float* W2b_l = (const float*)d_in[16];
    const float* b2b_l = (const float*)d_in[17];
    const float* W2b_r = (const float*)d_in[18];
    const float* W_ih = (const float*)d_in[19];
    const float* W_hh = (const float*)d_in[20];
    const float* b_ih = (const float*)d_in[21];
    const float* b_hh = (const float*)d_in[22];
    const float* W_att = (const float*)d_in[23];
    const float* b_att = (const float*)d_in[24];
    const float* W_p1 = (const float*)d_in[25];
    const float* b_p1 = (const float*)d_in[26];
    const float* W_p2 = (const float*)d_in[27];
    const float* b_p2 = (const float*)d_in[28];
    float* out = (float*)d_out;

    char* ws = (char*)d_ws;
    int*      cnt2  = (int*)(ws + OFF_CNT2);
    int*      items = (int*)(ws + OFF_ITEMS);
    int*      cnt1  = (int*)(ws + OFF_CNT1);
    float*    hsum  = (float*)(ws + OFF_HSUM);
    unsigned* gbm   = (unsigned*)(ws + OFF_GBM);
    int*      list1 = (int*)(ws + OFF_LIST1);
    float*    rnn   = (float*)(ws + OFF_RNN);

    hipMemsetAsync(d_ws, 0, WS_ZERO2, stream);
    hipMemsetAsync(ws + OFF_RNN, 0xFF, T * H * 4, stream);  // rnn sentinel

    dim3 g1((EQ + 255) / 256, T);
    k_find_e2<<<g1, 256, 0, stream>>>(e2_src, e2_dst, target_p, cnt2, items, gbm);

    k_scan_e1<<<g1, 256, 0, stream>>>(e1_src, e1_dst, cnt2, items, gbm, cnt1, list1);

    dim3 g3(MAXS, T);
    k_hitem<<<g3, 256, 0, stream>>>(x_item, x_inf, W1a_l, b1a_l, W1a_r,
                                    cnt2, items, cnt1, list1, hsum);

    k_gru<<<NB, 256, 0, stream>>>(x_inf, x_item, target_p,
                                  W1b_l, b1b_l, W1b_r, W2b_l, b2b_l, W2b_r,
                                  cnt2, items, hsum, W_ih, b_ih, W_hh, b_hh,
                                  W_att, b_att, W_p1, b_p1, W_p2, b_p2,
                                  rnn, out);
}

// Round 4
// 663.744 us; speedup vs baseline: 1.2181x; 1.2181x over previous
//
#include <hip/hip_runtime.h>
#include <math.h>

#define T 8
#define NI 20000
#define NK 50000
#define F 128
#define H 256
#define O 128
#define E 500000
#define G3 (3*H)          // 768
#define MAXS 256          // slot cap per timestep (E[slots]=25)
#define CAP1 256          // per-slot e1 edge cap (E[edges/slot]=10)
#define BMW 1568          // ceil(NK/32)
#define NB 8              // persistent GRU blocks
#define RPB 32            // h-indices per GRU block (H/NB)
#define EQ (E/4)          // int4 quads per timestep
#define SENT 0xFFFFFFFFu  // sentinel (-NaN bit pattern, unreachable from finite math)

// ---------------- workspace layout (bytes) ----------------
// zeroed prefix:
#define OFF_CNT2   0                        // T ints
#define OFF_ITEMS  32                       // T*MAXS ints
#define OFF_CNT1   (32 + T*MAXS*4)          // T*MAXS ints
#define OFF_HSUM   (OFF_CNT1 + T*MAXS*4)    // T*H floats
#define OFF_Z2SUM  (OFF_HSUM + T*H*4)       // T*F floats
#define OFF_GBM    (OFF_Z2SUM + T*F*4)      // T*BMW uints
#define WS_ZERO    (OFF_GBM + T*BMW*4)      // ~77 KB memset
// not zeroed (fully written before read):
#define OFF_LIST1  WS_ZERO                  // T*MAXS*CAP1 ints (2 MB)
// sentinel-filled (0xFF memset, contiguous):
#define OFF_RNN    (OFF_LIST1 + (size_t)T*MAXS*CAP1*4)  // T*H floats
#define OFF_OWS    (OFF_RNN + T*H*4)        // T*O floats
#define WS_USED    (OFF_OWS + T*O*4)

// K1: scan e2_dst (int4) for edges into target; record src items (slots),
// set global item bitmap.
__global__ void k_find_e2(const int* __restrict__ e2_src, const int* __restrict__ e2_dst,
                          const int* __restrict__ target_p,
                          int* __restrict__ cnt2, int* __restrict__ items,
                          unsigned* __restrict__ gbm) {
    int t = blockIdx.y;
    long q = (long)blockIdx.x * 256 + threadIdx.x;
    if (q >= EQ) return;
    int target = *target_p;
    const int4 d4 = ((const int4*)(e2_dst + (long)t * E))[q];
    int dd[4] = {d4.x, d4.y, d4.z, d4.w};
#pragma unroll
    for (int c = 0; c < 4; ++c) {
        if (dd[c] == target) {
            long j = q * 4 + c;
            int src = e2_src[(long)t * E + j];
            int pos = atomicAdd(&cnt2[t], 1);
            if (pos < MAXS) {
                items[t * MAXS + pos] = src;
                atomicOr(&gbm[t * BMW + (src >> 5)], 1u << (src & 31));
            }
        }
    }
}

// K2: scan e1_dst (int4) against global bitmap; matching edges append their
// src index into the slot's list.
__global__ void k_scan_e1(const int* __restrict__ e1_src, const int* __restrict__ e1_dst,
                          const int* __restrict__ cnt2, const int* __restrict__ items,
                          const unsigned* __restrict__ gbm,
                          int* __restrict__ cnt1, int* __restrict__ list1) {
    int t = blockIdx.y;
    long q = (long)blockIdx.x * 256 + threadIdx.x;
    if (q >= EQ) return;
    const unsigned* bm = gbm + t * BMW;
    const int4 d4 = ((const int4*)(e1_dst + (long)t * E))[q];
    int dd[4] = {d4.x, d4.y, d4.z, d4.w};
#pragma unroll
    for (int c = 0; c < 4; ++c) {
        int d = dd[c];
        if (!((bm[d >> 5] >> (d & 31)) & 1u)) continue;
        long j = q * 4 + c;
        int src = e1_src[(long)t * E + j];
        int ns = min(cnt2[t], MAXS);
        for (int i = 0; i < ns; ++i) {
            if (items[t * MAXS + i] == d) {
                int pos = atomicAdd(&cnt1[t * MAXS + i], 1);
                if (pos < CAP1) list1[((long)t * MAXS + i) * CAP1 + pos] = src;
            }
        }
    }
}

// K3: per slot, gather its e1 srcs, mean, then
// h_item = relu(mean @ W1a_l.T + b1a_l + x_item @ W1a_r.T); sum into hsum.
// Also accumulates x_item[item] into z2sum[t] (the layer-2 mean numerator),
// replacing k_gru's serial gather.
__global__ void k_hitem(const float* __restrict__ x_item, const float* __restrict__ x_inf,
                        const float* __restrict__ W1a_l, const float* __restrict__ b1a_l,
                        const float* __restrict__ W1a_r,
                        const int* __restrict__ cnt2, const int* __restrict__ items,
                        const int* __restrict__ cnt1, const int* __restrict__ list1,
                        float* __restrict__ hsum, float* __restrict__ z2sum) {
    int t = blockIdx.y, slot = blockIdx.x;
    int ns = min(cnt2[t], MAXS);
    if (slot >= ns) return;
    __shared__ float z1[F], xk[F];
    int item = items[t * MAXS + slot];
    int ne = cnt1[t * MAXS + slot];
    float inv = 1.0f / fmaxf((float)ne, 1.0f);
    int nr = min(ne, CAP1);
    if (threadIdx.x < F) {
        int f = threadIdx.x;
        const int* lst = list1 + ((long)t * MAXS + slot) * CAP1;
        float s = 0.0f;
        for (int e = 0; e < nr; ++e)
            s += x_inf[((long)t * NI + lst[e]) * F + f];
        z1[f] = s * inv;
        float xv = x_item[((long)t * NK + item) * F + f];
        xk[f] = xv;
        atomicAdd(&z2sum[t * F + f], xv);
    }
    __syncthreads();
    int h = threadIdx.x;  // 256 == H
    float acc = b1a_l[h];
    const float* wl = W1a_l + h * F;
    const float* wr = W1a_r + h * F;
    for (int f = 0; f < F; ++f) acc += z1[f] * wl[f] + xk[f] * wr[f];
    acc = fmaxf(acc, 0.0f);
    atomicAdd(&hsum[t * H + h], acc);
}

// K4 v4: t-split phase 1 (block b -> o[t=b]) + fence-free sentinel exchange
// of o and h. No __threadfence / release-acquire anywhere: values themselves
// are the flags (workspace pre-filled with 0xFF = -NaN, unreachable).
__global__ void __launch_bounds__(256, 1)
k_gru(const float* __restrict__ x_inf, const int* __restrict__ target_p,
      const float* __restrict__ W1b_l, const float* __restrict__ b1b_l,
      const float* __restrict__ W1b_r,
      const float* __restrict__ W2b_l, const float* __restrict__ b2b_l,
      const float* __restrict__ W2b_r,
      const int* __restrict__ cnt2,
      const float* __restrict__ hsum, const float* __restrict__ z2sum,
      const float* __restrict__ W_ih, const float* __restrict__ b_ih,
      const float* __restrict__ W_hh, const float* __restrict__ b_hh,
      const float* __restrict__ W_att, const float* __restrict__ b_att,
      const float* __restrict__ W_p1, const float* __restrict__ b_p1,
      const float* __restrict__ W_p2, const float* __restrict__ b_p2,
      float* __restrict__ rnn, float* __restrict__ o_ws, float* __restrict__ out) {
    __shared__ float w[3 * RPB][H];   // 96 KiB  W_hh slice
    __shared__ float h[H];
    __shared__ float srnn[T][H];      // 8 KiB
    __shared__ float satt[T], tmp[H], hid[128];
    __shared__ float z2[F], xt[F], hinf[H], mh[H];
    __shared__ float so_all[T][O];    // 4 KiB
    __shared__ float sgi[T][3][RPB];  // 3 KiB
    int b = blockIdx.x, tid = threadIdx.x;
    int wv = tid >> 6, lane = tid & 63;
    unsigned* rnn_u = (unsigned*)rnn;
    unsigned* o_u = (unsigned*)o_ws;

    // ---- phase 1: o[t=b] only ----
    {
        int t = b;
        int target = *target_p;
        float c2 = fmaxf((float)cnt2[t], 1.0f);
        if (tid < F) {
            z2[tid] = z2sum[t * F + tid] / c2;
            xt[tid] = x_inf[((long)t * NI + target) * F + tid];
        }
        mh[tid] = hsum[t * H + tid] / c2;
        __syncthreads();
        // hinf rows, wave-per-row (coalesced weight reads)
        for (int r = wv; r < H; r += 4) {
            float wl0 = W1b_l[r * F + lane], wl1 = W1b_l[r * F + 64 + lane];
            float wr0 = W1b_r[r * F + lane], wr1 = W1b_r[r * F + 64 + lane];
            float s = wl0 * z2[lane] + wl1 * z2[lane + 64]
                    + wr0 * xt[lane] + wr1 * xt[lane + 64];
            for (int off = 32; off; off >>= 1) s += __shfl_down(s, off);
            if (lane == 0) hinf[r] = fmaxf(s + b1b_l[r], 0.0f);
        }
        __syncthreads();
        // o rows, wave-per-row; publish via relaxed agent atomics (data-as-flag)
        for (int r = wv; r < O; r += 4) {
            float s = 0.0f;
            for (int c = 0; c < 4; ++c) {
                int k = lane + 64 * c;
                s += W2b_l[r * H + k] * mh[k] + W2b_r[r * H + k] * hinf[k];
            }
            for (int off = 32; off; off >>= 1) s += __shfl_down(s, off);
            if (lane == 0)
                __hip_atomic_store(&o_u[t * O + r], __float_as_uint(s + b2b_l[r]),
                                   __ATOMIC_RELAXED, __HIP_MEMORY_SCOPE_AGENT);
        }
    }

    // ---- W_hh slice -> LDS (overlaps other blocks finishing phase 1) ----
    for (int idx = tid; idx < 3 * RPB * H; idx += 256) {
        int r = idx >> 8, k = idx & 255;
        int g = r / RPB, j = r - g * RPB;
        w[r][k] = W_hh[((long)(g * H + b * RPB + j)) * H + k];
    }

    // ---- spin-gather all o vectors ----
    for (int idx = tid; idx < T * O; idx += 256) {
        unsigned v;
        do {
            v = __hip_atomic_load(&o_u[idx], __ATOMIC_RELAXED,
                                  __HIP_MEMORY_SCOPE_AGENT);
            if (v != SENT) break;
            __builtin_amdgcn_s_sleep(1);
        } while (true);
        so_all[idx >> 7][idx & 127] = __uint_as_float(v);
    }
    h[tid] = 0.0f;
    __syncthreads();

    // ---- phase 2: own gi rows, into LDS ----
    for (int lr = wv; lr < 3 * RPB; lr += 4) {
        int g = lr >> 5, j = lr & 31;
        int r = g * H + b * RPB + j;
        float w0 = W_ih[(long)r * O + lane];
        float w1 = W_ih[(long)r * O + 64 + lane];
        float bi = b_ih[r];
        for (int t = 0; t < T; ++t) {
            float s = w0 * so_all[t][lane] + w1 * so_all[t][lane + 64];
            for (int off = 32; off; off >>= 1) s += __shfl_down(s, off);
            if (lane == 0) sgi[t][g][j] = s + bi;
        }
    }
    __syncthreads();

    // ---- GRU recurrence: h exchanged via sentinel data spins ----
    for (int t = 0; t < T; ++t) {
        for (int j = wv; j < RPB; j += 4) {
            float sr = 0.f, sz = 0.f, sn = 0.f;
            for (int c = 0; c < 4; ++c) {
                int k = lane + 64 * c;
                float hk = h[k];
                sr += w[j][k] * hk;
                sz += w[RPB + j][k] * hk;
                sn += w[2 * RPB + j][k] * hk;
            }
            for (int off = 32; off; off >>= 1) {
                sr += __shfl_down(sr, off);
                sz += __shfl_down(sz, off);
                sn += __shfl_down(sn, off);
            }
            if (lane == 0) {
                int i = b * RPB + j;
                float r = 1.0f / (1.0f + expf(-(sgi[t][0][j] + sr + b_hh[i])));
                float z = 1.0f / (1.0f + expf(-(sgi[t][1][j] + sz + b_hh[H + i])));
                float n = tanhf(sgi[t][2][j] + r * (sn + b_hh[2 * H + i]));
                float hn = (1.0f - z) * n + z * h[i];
                __hip_atomic_store(&rnn_u[t * H + i], __float_as_uint(hn),
                                   __ATOMIC_RELAXED, __HIP_MEMORY_SCOPE_AGENT);
            }
        }
        __syncthreads();   // all waves done reading old h
        unsigned v;
        do {
            v = __hip_atomic_load(&rnn_u[t * H + tid], __ATOMIC_RELAXED,
                                  __HIP_MEMORY_SCOPE_AGENT);
            if (v != SENT) break;
            __builtin_amdgcn_s_sleep(1);
        } while (true);
        float hv = __uint_as_float(v);
        h[tid] = hv;
        srnn[t][tid] = hv;
        __syncthreads();   // h ready for next step
    }
    if (b != 0) return;
    // ---- attention + head (block 0, from srnn) ----
    {   // att scores: 32 lanes per t
        int tt = tid >> 5, l32 = tid & 31;
        float a = 0.f;
        for (int c = 0; c < 8; ++c) {
            int k = l32 + 32 * c;
            a += W_att[k] * srnn[tt][k];
        }
        for (int off = 16; off; off >>= 1) a += __shfl_down(a, off, 32);
        if (l32 == 0) satt[tt] = a + b_att[0];
    }
    __syncthreads();
    if (tid == 0) {
        float m = satt[0];
        for (int t = 1; t < T; ++t) m = fmaxf(m, satt[t]);
        float s = 0.f;
        for (int t = 0; t < T; ++t) { satt[t] = expf(satt[t] - m); s += satt[t]; }
        for (int t = 0; t < T; ++t) satt[t] /= s;
    }
    __syncthreads();
    {
        float ctx = 0.f;
        for (int t = 0; t < T; ++t) ctx += satt[t] * srnn[t][tid];
        tmp[tid] = ctx;
    }
    __syncthreads();
    // hid rows, wave-per-row (coalesced W_p1 reads)
    for (int r = wv; r < 128; r += 4) {
        float s = 0.0f;
        for (int c = 0; c < 4; ++c) {
            int k = lane + 64 * c;
            s += W_p1[r * H + k] * tmp[k];
        }
        for (int off = 32; off; off >>= 1) s += __shfl_down(s, off);
        if (lane == 0) hid[r] = fmaxf(s + b_p1[r], 0.0f);
    }
    __syncthreads();
    if (tid < 64) {
        float s = W_p2[lane] * hid[lane] + W_p2[lane + 64] * hid[lane + 64];
        for (int off = 32; off; off >>= 1) s += __shfl_down(s, off);
        if (lane == 0) out[0] = s + b_p2[0];
    }
}

extern "C" void kernel_launch(void* const* d_in, const int* in_sizes, int n_in,
                              void* d_out, int out_size, void* d_ws, size_t ws_size,
                              hipStream_t stream) {
    const float* x_inf  = (const float*)d_in[0];
    const float* x_item = (const float*)d_in[1];
    const int* e1_src = (const int*)d_in[2];
    const int* e1_dst = (const int*)d_in[3];
    const int* e2_src = (const int*)d_in[4];
    const int* e2_dst = (const int*)d_in[5];
    const int* target_p = (const int*)d_in[6];
    const float* W1a_l = (const float*)d_in[7];
    const float* b1a_l = (const float*)d_in[8];
    const float* W1a_r = (const float*)d_in[9];
    const float* W1b_l = (const float*)d_in[10];
    const float* b1b_l = (const float*)d_in[11];
    const float* W1b_r = (const float*)d_in[12];
    const float* W2b_l = (const float*)d_in[16];
    const float* b2b_l = (const float*)d_in[17];
    const float* W2b_r = (const float*)d_in[18];
    const float* W_ih = (const float*)d_in[19];
    const float* W_hh = (const float*)d_in[20];
    const float* b_ih = (const float*)d_in[21];
    const float* b_hh = (const float*)d_in[22];
    const float* W_att = (const float*)d_in[23];
    const float* b_att = (const float*)d_in[24];
    const float* W_p1 = (const float*)d_in[25];
    const float* b_p1 = (const float*)d_in[26];
    const float* W_p2 = (const float*)d_in[27];
    const float* b_p2 = (const float*)d_in[28];
    float* out = (float*)d_out;

    char* ws = (char*)d_ws;
    int*      cnt2  = (int*)(ws + OFF_CNT2);
    int*      items = (int*)(ws + OFF_ITEMS);
    int*      cnt1  = (int*)(ws + OFF_CNT1);
    float*    hsum  = (float*)(ws + OFF_HSUM);
    float*    z2sum = (float*)(ws + OFF_Z2SUM);
    unsigned* gbm   = (unsigned*)(ws + OFF_GBM);
    int*      list1 = (int*)(ws + OFF_LIST1);
    float*    rnn   = (float*)(ws + OFF_RNN);
    float*    o_ws  = (float*)(ws + OFF_OWS);

    hipMemsetAsync(d_ws, 0, WS_ZERO, stream);
    hipMemsetAsync(ws + OFF_RNN, 0xFF, (T * H + T * O) * 4, stream);  // sentinels

    dim3 g1((EQ + 255) / 256, T);
    k_find_e2<<<g1, 256, 0, stream>>>(e2_src, e2_dst, target_p, cnt2, items, gbm);

    k_scan_e1<<<g1, 256, 0, stream>>>(e1_src, e1_dst, cnt2, items, gbm, cnt1, list1);

    dim3 g3(MAXS, T);
    k_hitem<<<g3, 256, 0, stream>>>(x_item, x_inf, W1a_l, b1a_l, W1a_r,
                                    cnt2, items, cnt1, list1, hsum, z2sum);

    k_gru<<<NB, 256, 0, stream>>>(x_inf, target_p,
                                  W1b_l, b1b_l, W1b_r, W2b_l, b2b_l, W2b_r,
                                  cnt2, hsum, z2sum, W_ih, b_ih, W_hh, b_hh,
                                  W_att, b_att, W_p1, b_p1, W_p2, b_p2,
                                  rnn, o_ws, out);
}

// Round 5
// 581.529 us; speedup vs baseline: 1.3903x; 1.1414x over previous
//
#include <hip/hip_runtime.h>
#include <math.h>

#define T 8
#define NI 20000
#define NK 50000
#define F 128
#define H 256
#define O 128
#define E 500000
#define G3 (3*H)          // 768
#define MAXS 256          // slot cap per timestep (E[slots]=25)
#define CAP1 256          // per-slot e1 edge cap (E[edges/slot]=10)
#define BMW 1568          // ceil(NK/32)
#define EQ (E/4)          // int4 quads per timestep

// ---------------- workspace layout (bytes) ----------------
// zeroed prefix:
#define OFF_CNT2   0                        // T ints
#define OFF_ITEMS  32                       // T*MAXS ints
#define OFF_CNT1   (32 + T*MAXS*4)          // T*MAXS ints
#define OFF_HSUM   (OFF_CNT1 + T*MAXS*4)    // T*H floats
#define OFF_Z2SUM  (OFF_HSUM + T*H*4)       // T*F floats
#define OFF_GBM    (OFF_Z2SUM + T*F*4)      // T*BMW uints
#define WS_ZERO    (OFF_GBM + T*BMW*4)      // ~77 KB memset
// not zeroed (fully written before read):
#define OFF_LIST1  WS_ZERO                  // T*MAXS*CAP1 ints (2 MB)
#define OFF_O      (OFF_LIST1 + (size_t)T*MAXS*CAP1*4)  // T*O floats
#define OFF_GI     (OFF_O + T*O*4)          // T*G3 floats
#define OFF_WHHT   (OFF_GI + T*G3*4)        // H*G3 floats (768 KB, transposed W_hh)
#define WS_USED    (OFF_WHHT + (size_t)H*G3*4)

// K0: tiled transpose W_hh[768][256] -> W_hhT[256][768] (both coalesced).
__global__ void k_prep(const float* __restrict__ W_hh, float* __restrict__ W_hhT) {
    __shared__ float tile[64][65];
    int r0 = blockIdx.x * 64;   // row tile of W_hh (12)
    int k0 = blockIdx.y * 64;   // col tile of W_hh (4)
    for (int idx = threadIdx.x; idx < 64 * 64; idx += 256) {
        int r = idx >> 6, k = idx & 63;
        tile[r][k] = W_hh[(long)(r0 + r) * H + k0 + k];
    }
    __syncthreads();
    for (int idx = threadIdx.x; idx < 64 * 64; idx += 256) {
        int k = idx >> 6, r = idx & 63;
        W_hhT[(long)(k0 + k) * G3 + r0 + r] = tile[r][k];
    }
}

// K1: scan e2_dst (int4) for edges into target; record src items (slots),
// set global item bitmap.
__global__ void k_find_e2(const int* __restrict__ e2_src, const int* __restrict__ e2_dst,
                          const int* __restrict__ target_p,
                          int* __restrict__ cnt2, int* __restrict__ items,
                          unsigned* __restrict__ gbm) {
    int t = blockIdx.y;
    long q = (long)blockIdx.x * 256 + threadIdx.x;
    if (q >= EQ) return;
    int target = *target_p;
    const int4 d4 = ((const int4*)(e2_dst + (long)t * E))[q];
    int dd[4] = {d4.x, d4.y, d4.z, d4.w};
#pragma unroll
    for (int c = 0; c < 4; ++c) {
        if (dd[c] == target) {
            long j = q * 4 + c;
            int src = e2_src[(long)t * E + j];
            int pos = atomicAdd(&cnt2[t], 1);
            if (pos < MAXS) {
                items[t * MAXS + pos] = src;
                atomicOr(&gbm[t * BMW + (src >> 5)], 1u << (src & 31));
            }
        }
    }
}

// K2: scan e1_dst (int4) against global bitmap; matching edges append their
// src index into the slot's list.
__global__ void k_scan_e1(const int* __restrict__ e1_src, const int* __restrict__ e1_dst,
                          const int* __restrict__ cnt2, const int* __restrict__ items,
                          const unsigned* __restrict__ gbm,
                          int* __restrict__ cnt1, int* __restrict__ list1) {
    int t = blockIdx.y;
    long q = (long)blockIdx.x * 256 + threadIdx.x;
    if (q >= EQ) return;
    const unsigned* bm = gbm + t * BMW;
    const int4 d4 = ((const int4*)(e1_dst + (long)t * E))[q];
    int dd[4] = {d4.x, d4.y, d4.z, d4.w};
#pragma unroll
    for (int c = 0; c < 4; ++c) {
        int d = dd[c];
        if (!((bm[d >> 5] >> (d & 31)) & 1u)) continue;
        long j = q * 4 + c;
        int src = e1_src[(long)t * E + j];
        int ns = min(cnt2[t], MAXS);
        for (int i = 0; i < ns; ++i) {
            if (items[t * MAXS + i] == d) {
                int pos = atomicAdd(&cnt1[t * MAXS + i], 1);
                if (pos < CAP1) list1[((long)t * MAXS + i) * CAP1 + pos] = src;
            }
        }
    }
}

// K3: per slot, gather its e1 srcs, mean, then
// h_item = relu(mean @ W1a_l.T + b1a_l + x_item @ W1a_r.T); sum into hsum.
// Also accumulates x_item[item] into z2sum[t] (layer-2 mean numerator).
__global__ void k_hitem(const float* __restrict__ x_item, const float* __restrict__ x_inf,
                        const float* __restrict__ W1a_l, const float* __restrict__ b1a_l,
                        const float* __restrict__ W1a_r,
                        const int* __restrict__ cnt2, const int* __restrict__ items,
                        const int* __restrict__ cnt1, const int* __restrict__ list1,
                        float* __restrict__ hsum, float* __restrict__ z2sum) {
    int t = blockIdx.y, slot = blockIdx.x;
    int ns = min(cnt2[t], MAXS);
    if (slot >= ns) return;
    __shared__ float z1[F], xk[F];
    int item = items[t * MAXS + slot];
    int ne = cnt1[t * MAXS + slot];
    float inv = 1.0f / fmaxf((float)ne, 1.0f);
    int nr = min(ne, CAP1);
    if (threadIdx.x < F) {
        int f = threadIdx.x;
        const int* lst = list1 + ((long)t * MAXS + slot) * CAP1;
        float s = 0.0f;
        for (int e = 0; e < nr; ++e)
            s += x_inf[((long)t * NI + lst[e]) * F + f];
        z1[f] = s * inv;
        float xv = x_item[((long)t * NK + item) * F + f];
        xk[f] = xv;
        atomicAdd(&z2sum[t * F + f], xv);
    }
    __syncthreads();
    int h = threadIdx.x;  // 256 == H
    float acc = b1a_l[h];
    const float* wl = W1a_l + h * F;
    const float* wr = W1a_r + h * F;
    for (int f = 0; f < F; ++f) acc += z1[f] * wl[f] + xk[f] * wr[f];
    acc = fmaxf(acc, 0.0f);
    atomicAdd(&hsum[t * H + h], acc);
}

// K4: per t: hinf (wave-per-row), then o[t] = mh @ W2b_l.T + b2b_l + hinf @ W2b_r.T
__global__ void k_layer2(const float* __restrict__ x_inf, const int* __restrict__ target_p,
                         const float* __restrict__ W1b_l, const float* __restrict__ b1b_l,
                         const float* __restrict__ W1b_r,
                         const float* __restrict__ W2b_l, const float* __restrict__ b2b_l,
                         const float* __restrict__ W2b_r,
                         const int* __restrict__ cnt2,
                         const float* __restrict__ hsum, const float* __restrict__ z2sum,
                         float* __restrict__ o_ws) {
    int t = blockIdx.x, tid = threadIdx.x;
    int wv = tid >> 6, lane = tid & 63;
    __shared__ float z2[F], xt[F], hinf[H], mh[H];
    int target = *target_p;
    float c2 = fmaxf((float)cnt2[t], 1.0f);
    if (tid < F) {
        z2[tid] = z2sum[t * F + tid] / c2;
        xt[tid] = x_inf[((long)t * NI + target) * F + tid];
    }
    mh[tid] = hsum[t * H + tid] / c2;
    __syncthreads();
    for (int r = wv; r < H; r += 4) {
        float wl0 = W1b_l[r * F + lane], wl1 = W1b_l[r * F + 64 + lane];
        float wr0 = W1b_r[r * F + lane], wr1 = W1b_r[r * F + 64 + lane];
        float s = wl0 * z2[lane] + wl1 * z2[lane + 64]
                + wr0 * xt[lane] + wr1 * xt[lane + 64];
        for (int off = 32; off; off >>= 1) s += __shfl_down(s, off);
        if (lane == 0) hinf[r] = fmaxf(s + b1b_l[r], 0.0f);
    }
    __syncthreads();
    for (int r = wv; r < O; r += 4) {
        float s = 0.0f;
        for (int c = 0; c < 4; ++c) {
            int k = lane + 64 * c;
            s += W2b_l[r * H + k] * mh[k] + W2b_r[r * H + k] * hinf[k];
        }
        for (int off = 32; off; off >>= 1) s += __shfl_down(s, off);
        if (lane == 0) o_ws[t * O + r] = s + b2b_l[r];
    }
}

// K5: gi[t] = W_ih @ o[t] + b_ih (wave per row, massively parallel).
__global__ void k_gi(const float* __restrict__ o_ws, const float* __restrict__ W_ih,
                     const float* __restrict__ b_ih, float* __restrict__ gi) {
    int t = blockIdx.y;
    int wv = threadIdx.x >> 6, lane = threadIdx.x & 63;
    int row = blockIdx.x * 4 + wv;  // 0..767
    const float* w = W_ih + (long)row * O;
    const float* x = o_ws + t * O;
    float s = w[lane] * x[lane] + w[lane + 64] * x[lane + 64];
    for (int off = 32; off; off >>= 1) s += __shfl_down(s, off);
    if (lane == 0) gi[t * G3 + row] = s + b_ih[row];
}

// K6: SINGLE-BLOCK GRU + head. 1024 threads, zero inter-block communication.
// Per step: thread-per-row matvec gh = W_hhT^T h (768 KB coalesced L2 reads);
// t=0 skipped (h0=0 => gh=0). All state in LDS.
__global__ void __launch_bounds__(1024, 1)
k_gru(const float* __restrict__ gi_g, const float* __restrict__ W_hhT,
      const float* __restrict__ b_hh,
      const float* __restrict__ W_att, const float* __restrict__ b_att,
      const float* __restrict__ W_p1, const float* __restrict__ b_p1,
      const float* __restrict__ W_p2, const float* __restrict__ b_p2,
      float* __restrict__ out) {
    __shared__ float sgi[T][G3];      // 24 KiB
    __shared__ float sbhh[G3];        // 3 KiB
    __shared__ float gh[G3];          // 3 KiB
    __shared__ float hs[H];
    __shared__ float srnn[T][H];      // 8 KiB
    __shared__ float satt[T], tmp[H], hid[128];
    int tid = threadIdx.x;
    for (int i = tid; i < T * G3; i += 1024) sgi[i / G3][i % G3] = gi_g[i];
    for (int i = tid; i < G3; i += 1024) sbhh[i] = b_hh[i];
    if (tid < H) hs[tid] = 0.0f;
    __syncthreads();

    for (int t = 0; t < T; ++t) {
        if (tid < G3) {
            float g = 0.0f;
            if (t > 0) {   // h=0 at t=0 => gh=0
                const float* wp = W_hhT + tid;
                float a0 = 0.f, a1 = 0.f, a2 = 0.f, a3 = 0.f;
#pragma unroll 8
                for (int k = 0; k < H; k += 4) {
                    a0 += wp[(k + 0) * G3] * hs[k + 0];
                    a1 += wp[(k + 1) * G3] * hs[k + 1];
                    a2 += wp[(k + 2) * G3] * hs[k + 2];
                    a3 += wp[(k + 3) * G3] * hs[k + 3];
                }
                g = (a0 + a1) + (a2 + a3);
            }
            gh[tid] = g;
        }
        __syncthreads();
        if (tid < H) {
            int i = tid;
            float r = 1.0f / (1.0f + expf(-(sgi[t][i] + gh[i] + sbhh[i])));
            float z = 1.0f / (1.0f + expf(-(sgi[t][H + i] + gh[H + i] + sbhh[H + i])));
            float n = tanhf(sgi[t][2 * H + i] + r * (gh[2 * H + i] + sbhh[2 * H + i]));
            float hn = (1.0f - z) * n + z * hs[i];
            hs[i] = hn;
            srnn[t][i] = hn;
        }
        __syncthreads();
    }

    // ---- attention + head ----
    if (tid < 256) {  // 32 lanes per t
        int tt = tid >> 5, l32 = tid & 31;
        float a = 0.f;
        for (int c = 0; c < 8; ++c) {
            int k = l32 + 32 * c;
            a += W_att[k] * srnn[tt][k];
        }
        for (int off = 16; off; off >>= 1) a += __shfl_down(a, off, 32);
        if (l32 == 0) satt[tt] = a + b_att[0];
    }
    __syncthreads();
    if (tid == 0) {
        float m = satt[0];
        for (int t = 1; t < T; ++t) m = fmaxf(m, satt[t]);
        float s = 0.f;
        for (int t = 0; t < T; ++t) { satt[t] = expf(satt[t] - m); s += satt[t]; }
        for (int t = 0; t < T; ++t) satt[t] /= s;
    }
    __syncthreads();
    if (tid < H) {
        float ctx = 0.f;
        for (int t = 0; t < T; ++t) ctx += satt[t] * srnn[t][tid];
        tmp[tid] = ctx;
    }
    __syncthreads();
    {
        int wv = tid >> 6, lane = tid & 63;
        for (int r = wv; r < 128; r += 16) {
            float s = 0.0f;
            for (int c = 0; c < 4; ++c) {
                int k = lane + 64 * c;
                s += W_p1[(long)r * H + k] * tmp[k];
            }
            for (int off = 32; off; off >>= 1) s += __shfl_down(s, off);
            if (lane == 0) hid[r] = fmaxf(s + b_p1[r], 0.0f);
        }
    }
    __syncthreads();
    if (tid < 64) {
        float s = W_p2[tid] * hid[tid] + W_p2[tid + 64] * hid[tid + 64];
        for (int off = 32; off; off >>= 1) s += __shfl_down(s, off);
        if (tid == 0) out[0] = s + b_p2[0];
    }
}

extern "C" void kernel_launch(void* const* d_in, const int* in_sizes, int n_in,
                              void* d_out, int out_size, void* d_ws, size_t ws_size,
                              hipStream_t stream) {
    const float* x_inf  = (const float*)d_in[0];
    const float* x_item = (const float*)d_in[1];
    const int* e1_src = (const int*)d_in[2];
    const int* e1_dst = (const int*)d_in[3];
    const int* e2_src = (const int*)d_in[4];
    const int* e2_dst = (const int*)d_in[5];
    const int* target_p = (const int*)d_in[6];
    const float* W1a_l = (const float*)d_in[7];
    const float* b1a_l = (const float*)d_in[8];
    const float* W1a_r = (const float*)d_in[9];
    const float* W1b_l = (const float*)d_in[10];
    const float* b1b_l = (const float*)d_in[11];
    const float* W1b_r = (const float*)d_in[12];
    const float* W2b_l = (const float*)d_in[16];
    const float* b2b_l = (const float*)d_in[17];
    const float* W2b_r = (const float*)d_in[18];
    const float* W_ih = (const float*)d_in[19];
    const float* W_hh = (const float*)d_in[20];
    const float* b_ih = (const float*)d_in[21];
    const float* b_hh = (const float*)d_in[22];
    const float* W_att = (const float*)d_in[23];
    const float* b_att = (const float*)d_in[24];
    const float* W_p1 = (const float*)d_in[25];
    const float* b_p1 = (const float*)d_in[26];
    const float* W_p2 = (const float*)d_in[27];
    const float* b_p2 = (const float*)d_in[28];
    float* out = (float*)d_out;

    char* ws = (char*)d_ws;
    int*      cnt2  = (int*)(ws + OFF_CNT2);
    int*      items = (int*)(ws + OFF_ITEMS);
    int*      cnt1  = (int*)(ws + OFF_CNT1);
    float*    hsum  = (float*)(ws + OFF_HSUM);
    float*    z2sum = (float*)(ws + OFF_Z2SUM);
    unsigned* gbm   = (unsigned*)(ws + OFF_GBM);
    int*      list1 = (int*)(ws + OFF_LIST1);
    float*    o_ws  = (float*)(ws + OFF_O);
    float*    gi    = (float*)(ws + OFF_GI);
    float*    whhT  = (float*)(ws + OFF_WHHT);

    hipMemsetAsync(d_ws, 0, WS_ZERO, stream);

    k_prep<<<dim3(12, 4), 256, 0, stream>>>(W_hh, whhT);

    dim3 g1((EQ + 255) / 256, T);
    k_find_e2<<<g1, 256, 0, stream>>>(e2_src, e2_dst, target_p, cnt2, items, gbm);

    k_scan_e1<<<g1, 256, 0, stream>>>(e1_src, e1_dst, cnt2, items, gbm, cnt1, list1);

    dim3 g3(MAXS, T);
    k_hitem<<<g3, 256, 0, stream>>>(x_item, x_inf, W1a_l, b1a_l, W1a_r,
                                    cnt2, items, cnt1, list1, hsum, z2sum);

    k_layer2<<<T, 256, 0, stream>>>(x_inf, target_p, W1b_l, b1b_l, W1b_r,
                                    W2b_l, b2b_l, W2b_r, cnt2, hsum, z2sum, o_ws);

    dim3 g5(G3 / 4, T);
    k_gi<<<g5, 256, 0, stream>>>(o_ws, W_ih, b_ih, gi);

    k_gru<<<1, 1024, 0, stream>>>(gi, whhT, b_hh, W_att, b_att,
                                  W_p1, b_p1, W_p2, b_p2, out);
}